// Round 7
// baseline (56.249 us; speedup 1.0000x reference)
//
#include <hip/hip_runtime.h>

// B=4096, Z=128, DEG=16, E=2048. out[b,i,j]=1 except out[b,src[e],dst[e]]=beta[b,e].
// src[e]=e/16 -> row i owns edges [16i,16i+16).
//
// R2 structure (best measured: 50.6us) with EXACTLY ONE change: output stores
// are nontemporal (stream past L2 -> no write-allocate + dirty-evict double
// handling for the 256 MiB once-written stream).

#define ZONES 128
#define NB    32   // batches per block

typedef float f32x4 __attribute__((ext_vector_type(4)));

__device__ __forceinline__ float fast_tanh(float v) {
    float e = __expf(2.0f * v);
    return 1.0f - 2.0f * __builtin_amdgcn_rcpf(e + 1.0f);
}
__device__ __forceinline__ float fast_sigmoid(float v) {
    return __builtin_amdgcn_rcpf(1.0f + __expf(-v));
}

__global__ __launch_bounds__(256) void fused_edge_mlp(
    const float* __restrict__ x,
    const int*   __restrict__ dst,
    const float* __restrict__ W1,
    const float* __restrict__ b1,
    const float* __restrict__ W2,
    const float* __restrict__ b2,
    const float* __restrict__ W3,
    const float* __restrict__ b3,
    float* __restrict__ out)
{
    // [parity][batch-half][8 rows * 128 cols] = 16 KB
    __shared__ float buf[2][2][8 * ZONES];

    const int tid  = threadIdx.x;
    const int rg   = blockIdx.x;          // row group: rows rg*8 .. rg*8+7
    const int b0   = blockIdx.y * NB;     // batch base

    const int boff = tid >> 7;            // 0/1: which batch of the pair
    const int t    = tid & 127;           // edge slot within row group
    const int e    = rg * 128 + t;        // global edge id
    const int srow = rg * 8 + (t >> 4);   // source zone (output row)
    const int dcol = dst[e];              // destination zone (output col)

    // hoist edge weights to registers (vectorized loads)
    float w1[8], b1v[4], w2[16], b2v[4], w3[4];
    *(float4*)&w1[0]  = ((const float4*)(W1 + e * 8))[0];
    *(float4*)&w1[4]  = ((const float4*)(W1 + e * 8))[1];
    *(float4*)&b1v[0] = ((const float4*)(b1 + e * 4))[0];
    *(float4*)&w2[0]  = ((const float4*)(W2 + e * 16))[0];
    *(float4*)&w2[4]  = ((const float4*)(W2 + e * 16))[1];
    *(float4*)&w2[8]  = ((const float4*)(W2 + e * 16))[2];
    *(float4*)&w2[12] = ((const float4*)(W2 + e * 16))[3];
    *(float4*)&b2v[0] = ((const float4*)(b2 + e * 4))[0];
    *(float4*)&w3[0]  = ((const float4*)(W3 + e * 4))[0];
    const float b3s = b3[e];

    // init ALL buffers to 1.0 exactly once; beta slots are batch-invariant
    f32x4* f4 = (f32x4*)buf;
    const f32x4 ones4 = {1.f, 1.f, 1.f, 1.f};
    #pragma unroll
    for (int i = 0; i < 4; ++i) f4[tid + 256 * i] = ones4;
    __syncthreads();

    f32x4* out4 = (f32x4*)out;

    #pragma unroll 4
    for (int it = 0; it < NB / 2; ++it) {
        const int p = it & 1;
        const int b = b0 + it * 2 + boff;

        const float xs = x[b * ZONES + srow];
        const float xd = x[b * ZONES + dcol];

        float h1[4];
        #pragma unroll
        for (int o = 0; o < 4; ++o)
            h1[o] = fast_tanh(fmaf(xs, w1[o], fmaf(xd, w1[4 + o], b1v[o])));

        float h2[4];
        #pragma unroll
        for (int o = 0; o < 4; ++o) {
            float z = b2v[o];
            #pragma unroll
            for (int k = 0; k < 4; ++k)
                z = fmaf(h1[k], w2[k * 4 + o], z);
            h2[o] = fast_tanh(z);
        }

        float z = b3s;
        #pragma unroll
        for (int o = 0; o < 4; ++o)
            z = fmaf(h2[o], w3[o], z);
        const float beta = fast_sigmoid(z);

        // scatter beta (16 distinct cols/row, positions fixed across batches)
        buf[p][boff][(t >> 4) * 128 + dcol] = beta;
        __syncthreads();

        // coalesced NONTEMPORAL store of both batches' 8 rows (4 KB each)
        #pragma unroll
        for (int bb = 0; bb < 2; ++bb) {
            const int bw = b0 + it * 2 + bb;
            const f32x4 v = ((f32x4*)buf[p][bb])[tid];
            __builtin_nontemporal_store(
                v, &out4[(size_t)bw * (ZONES * ZONES / 4) + rg * 256 + tid]);
        }
        // no trailing barrier: next iter writes the OTHER parity buffer;
        // this parity is reused only after the next iteration's barrier.
    }
}

extern "C" void kernel_launch(void* const* d_in, const int* in_sizes, int n_in,
                              void* d_out, int out_size, void* d_ws, size_t ws_size,
                              hipStream_t stream) {
    // setup_inputs order: x, dtPt, src, dst, W1, b1, W2, b2, W3, b3
    const float* x   = (const float*)d_in[0];
    const int*   dst = (const int*)  d_in[3];
    const float* W1  = (const float*)d_in[4];
    const float* b1  = (const float*)d_in[5];
    const float* W2  = (const float*)d_in[6];
    const float* b2  = (const float*)d_in[7];
    const float* W3  = (const float*)d_in[8];
    const float* b3  = (const float*)d_in[9];
    float* out = (float*)d_out;

    const int B = in_sizes[0] / ZONES;     // 4096
    dim3 grid(ZONES / 8, B / NB);          // (16, 128) = 2048 blocks
    fused_edge_mlp<<<grid, 256, 0, stream>>>(x, dst, W1, b1, W2, b2, W3, b3, out);
}

// Round 8
// 53.510 us; speedup vs baseline: 1.0512x; 1.0512x over previous
//
#include <hip/hip_runtime.h>

// B=4096, Z=128, DEG=16, E=2048. out[b,i,j]=1 except out[b,src[e],dst[e]]=beta[b,e].
// src[e]=e/16 -> row i owns edges [16i,16i+16).
//
// FINAL: R2 structure — best of 6 measured variants (50.6us; write-bandwidth
// bound: 256 MiB stream at ~5.3 TB/s avg incl. launch/ramp; fill-kernel
// reference is 6.9 TB/s at 4x the size).
//  * scatter positions are batch-invariant -> LDS ones-init ONCE
//  * ping-pong parity buffers -> 1 barrier/iteration
//  * per-thread edge weights (37 f32) hoisted to registers for NB=32 batches
//  * fast tanh/sigmoid via v_exp_f32 (err ~1e-6 << 2e-2 threshold)
//  * plain (cached) stores: L2 write-buffering helps; nt stores cost +11%.

#define ZONES 128
#define NB    32   // batches per block

typedef float f32x4 __attribute__((ext_vector_type(4)));

__device__ __forceinline__ float fast_tanh(float v) {
    float e = __expf(2.0f * v);
    return 1.0f - 2.0f * __builtin_amdgcn_rcpf(e + 1.0f);
}
__device__ __forceinline__ float fast_sigmoid(float v) {
    return __builtin_amdgcn_rcpf(1.0f + __expf(-v));
}

__global__ __launch_bounds__(256) void fused_edge_mlp(
    const float* __restrict__ x,
    const int*   __restrict__ dst,
    const float* __restrict__ W1,
    const float* __restrict__ b1,
    const float* __restrict__ W2,
    const float* __restrict__ b2,
    const float* __restrict__ W3,
    const float* __restrict__ b3,
    float* __restrict__ out)
{
    // [parity][batch-half][8 rows * 128 cols] = 16 KB
    __shared__ float buf[2][2][8 * ZONES];

    const int tid  = threadIdx.x;
    const int rg   = blockIdx.x;          // row group: rows rg*8 .. rg*8+7
    const int b0   = blockIdx.y * NB;     // batch base

    const int boff = tid >> 7;            // 0/1: which batch of the pair
    const int t    = tid & 127;           // edge slot within row group
    const int e    = rg * 128 + t;        // global edge id
    const int srow = rg * 8 + (t >> 4);   // source zone (output row)
    const int dcol = dst[e];              // destination zone (output col)

    // hoist edge weights to registers (vectorized loads)
    float w1[8], b1v[4], w2[16], b2v[4], w3[4];
    *(float4*)&w1[0]  = ((const float4*)(W1 + e * 8))[0];
    *(float4*)&w1[4]  = ((const float4*)(W1 + e * 8))[1];
    *(float4*)&b1v[0] = ((const float4*)(b1 + e * 4))[0];
    *(float4*)&w2[0]  = ((const float4*)(W2 + e * 16))[0];
    *(float4*)&w2[4]  = ((const float4*)(W2 + e * 16))[1];
    *(float4*)&w2[8]  = ((const float4*)(W2 + e * 16))[2];
    *(float4*)&w2[12] = ((const float4*)(W2 + e * 16))[3];
    *(float4*)&b2v[0] = ((const float4*)(b2 + e * 4))[0];
    *(float4*)&w3[0]  = ((const float4*)(W3 + e * 4))[0];
    const float b3s = b3[e];

    // init ALL buffers to 1.0 exactly once; beta slots are batch-invariant
    f32x4* f4 = (f32x4*)buf;
    const f32x4 ones4 = {1.f, 1.f, 1.f, 1.f};
    #pragma unroll
    for (int i = 0; i < 4; ++i) f4[tid + 256 * i] = ones4;
    __syncthreads();

    f32x4* out4 = (f32x4*)out;

    #pragma unroll 4
    for (int it = 0; it < NB / 2; ++it) {
        const int p = it & 1;
        const int b = b0 + it * 2 + boff;

        const float xs = x[b * ZONES + srow];
        const float xd = x[b * ZONES + dcol];

        float h1[4];
        #pragma unroll
        for (int o = 0; o < 4; ++o)
            h1[o] = fast_tanh(fmaf(xs, w1[o], fmaf(xd, w1[4 + o], b1v[o])));

        float h2[4];
        #pragma unroll
        for (int o = 0; o < 4; ++o) {
            float z = b2v[o];
            #pragma unroll
            for (int k = 0; k < 4; ++k)
                z = fmaf(h1[k], w2[k * 4 + o], z);
            h2[o] = fast_tanh(z);
        }

        float z = b3s;
        #pragma unroll
        for (int o = 0; o < 4; ++o)
            z = fmaf(h2[o], w3[o], z);
        const float beta = fast_sigmoid(z);

        // scatter beta (16 distinct cols/row, positions fixed across batches)
        buf[p][boff][(t >> 4) * 128 + dcol] = beta;
        __syncthreads();

        // coalesced store of both batches' 8 rows (4 KB contiguous each)
        #pragma unroll
        for (int bb = 0; bb < 2; ++bb) {
            const int bw = b0 + it * 2 + bb;
            out4[(size_t)bw * (ZONES * ZONES / 4) + rg * 256 + tid] =
                ((f32x4*)buf[p][bb])[tid];
        }
        // no trailing barrier: next iter writes the OTHER parity buffer;
        // this parity is reused only after the next iteration's barrier.
    }
}

extern "C" void kernel_launch(void* const* d_in, const int* in_sizes, int n_in,
                              void* d_out, int out_size, void* d_ws, size_t ws_size,
                              hipStream_t stream) {
    // setup_inputs order: x, dtPt, src, dst, W1, b1, W2, b2, W3, b3
    const float* x   = (const float*)d_in[0];
    const int*   dst = (const int*)  d_in[3];
    const float* W1  = (const float*)d_in[4];
    const float* b1  = (const float*)d_in[5];
    const float* W2  = (const float*)d_in[6];
    const float* b2  = (const float*)d_in[7];
    const float* W3  = (const float*)d_in[8];
    const float* b3  = (const float*)d_in[9];
    float* out = (float*)d_out;

    const int B = in_sizes[0] / ZONES;     // 4096
    dim3 grid(ZONES / 8, B / NB);          // (16, 128) = 2048 blocks
    fused_edge_mlp<<<grid, 256, 0, stream>>>(x, dst, W1, b1, W2, b2, W3, b3, out);
}